// Round 11
// baseline (654.899 us; speedup 1.0000x reference)
//
#include <hip/hip_runtime.h>
#include <hip/hip_bf16.h>

#define NN    8192
#define NFEAT 512
#define NHID  256
#define NCLASS 16
#define ELLW  256

typedef __hip_bfloat16 bf16;
typedef unsigned short u16;
typedef __bf16 bf16x8 __attribute__((ext_vector_type(8)));
typedef float  f32x4  __attribute__((ext_vector_type(4)));
typedef int    i32x4  __attribute__((ext_vector_type(4)));

// ---------------- dtype probe ----------------
__global__ __launch_bounds__(256) void probe_dtype2(const u16* __restrict__ a, int na,
                                                    const u16* __restrict__ b, int nb,
                                                    int* __restrict__ cnt) {
  int c = 0;
  for (int i = blockIdx.x * 256 + threadIdx.x; i < na; i += gridDim.x * 256)
    if (((a[i] >> 7) & 0xFF) == 0xFF) c++;
  for (int i = blockIdx.x * 256 + threadIdx.x; i < nb; i += gridDim.x * 256)
    if (((b[i] >> 7) & 0xFF) == 0xFF) c++;
  if (c) atomicAdd(cnt, c);
}

__global__ __launch_bounds__(256) void convert_bf(const void* __restrict__ src,
                                                  bf16* __restrict__ dst, int n,
                                                  const int* __restrict__ flagcnt) {
  bool isf32 = (*flagcnt > 16);
  int i = blockIdx.x * 256 + threadIdx.x;
  if (i < n) {
    if (isf32) dst[i] = __float2bfloat16(((const float*)src)[i]);
    else       dst[i] = ((const bf16*)src)[i];
  }
}

// ---- one launch: W1^T, Wa^T (bf16) + b1/avec/W3/b3 (f32) ----
__global__ __launch_bounds__(256) void convert_rest(const void* __restrict__ W1r,
                                                    const void* __restrict__ War,
                                                    const void* __restrict__ b1r,
                                                    const void* __restrict__ avr,
                                                    const void* __restrict__ W3r,
                                                    const void* __restrict__ b3r,
                                                    bf16* __restrict__ W1t,
                                                    bf16* __restrict__ Wat,
                                                    float* __restrict__ b1f,
                                                    float* __restrict__ avecf,
                                                    float* __restrict__ W3f,
                                                    float* __restrict__ b3f,
                                                    const int* __restrict__ flagcnt) {
  bool isf32 = (*flagcnt > 16);
  auto rd = [&](const void* p, int i) -> float {
    return isf32 ? ((const float*)p)[i] : __bfloat162float(((const bf16*)p)[i]);
  };
  const int n1 = NFEAT * NHID;
  const int n2 = n1 + NHID * NHID;
  const int n3 = n2 + NHID;
  const int n4 = n3 + 2 * NHID;
  const int n5 = n4 + NHID * NCLASS;
  const int n6 = n5 + NCLASS;
  for (int i = blockIdx.x * 256 + threadIdx.x; i < n6; i += gridDim.x * 256) {
    if (i < n1)      { int k = i / NHID, n = i % NHID; W1t[(size_t)n * NFEAT + k] = __float2bfloat16(rd(W1r, i)); }
    else if (i < n2) { int j = i - n1; int k = j / NHID, n = j % NHID; Wat[(size_t)n * NHID + k] = __float2bfloat16(rd(War, j)); }
    else if (i < n3) b1f[i - n2] = rd(b1r, i - n2);
    else if (i < n4) avecf[i - n3] = rd(avr, i - n3);
    else if (i < n5) W3f[i - n4] = rd(W3r, i - n4);
    else             b3f[i - n5] = rd(b3r, i - n5);
  }
}

// ------- adj -> ELL: ballot compaction, nontemporal adj reads -------
__global__ __launch_bounds__(256) void build_ell(const int* __restrict__ adj,
                                                 int* __restrict__ ell_cnt,
                                                 u16* __restrict__ ell_col) {
  __shared__ int cnt;
  int row = blockIdx.x;
  if (threadIdx.x == 0) cnt = 0;
  __syncthreads();
  const i32x4* arow = (const i32x4*)(adj + (size_t)row * NN);
  u16* crow = ell_col + (size_t)row * ELLW;
  int lane = threadIdx.x & 63;
  unsigned long long lt = ((unsigned long long)1 << lane) - 1;
  for (int j4 = threadIdx.x; j4 < NN / 4; j4 += 256) {
    i32x4 v = __builtin_nontemporal_load(&arow[j4]);
    unsigned long long m0 = __ballot(v.x != 0);
    unsigned long long m1 = __ballot(v.y != 0);
    unsigned long long m2 = __ballot(v.z != 0);
    unsigned long long m3 = __ballot(v.w != 0);
    int c0 = __popcll(m0), c1 = __popcll(m1), c2 = __popcll(m2), c3 = __popcll(m3);
    int total = c0 + c1 + c2 + c3;
    int base = 0;
    if (lane == 0 && total) base = atomicAdd(&cnt, total);
    base = __shfl(base, 0, 64);
    int col = j4 * 4;
    if (v.x) { int p = base + __popcll(m0 & lt);                 if (p < ELLW) crow[p] = (u16)col;       }
    if (v.y) { int p = base + c0 + __popcll(m1 & lt);            if (p < ELLW) crow[p] = (u16)(col + 1); }
    if (v.z) { int p = base + c0 + c1 + __popcll(m2 & lt);       if (p < ELLW) crow[p] = (u16)(col + 2); }
    if (v.w) { int p = base + c0 + c1 + c2 + __popcll(m3 & lt);  if (p < ELLW) crow[p] = (u16)(col + 3); }
  }
  __syncthreads();
  if (threadIdx.x == 0) ell_cnt[row] = cnt < ELLW ? cnt : ELLW;
}

// ------- bf16 MFMA GEMM, TK=64, register prefetch across barrier -------
#define TM 64
#define TN 64
#define LDSP 72

__global__ __launch_bounds__(256) void gemm_bt(const bf16* __restrict__ A, int lda,
                                               const bf16* __restrict__ Bt, int ldb,
                                               bf16* __restrict__ C, int ldc, int K) {
  __shared__ __align__(16) bf16 sA[TM * LDSP];
  __shared__ __align__(16) bf16 sB[TN * LDSP];
  int bm = blockIdx.x, bn = blockIdx.y;
  int t = threadIdx.x;
  int wave = t >> 6, lane = t & 63;
  int quad = lane >> 4, l16 = lane & 15;
  f32x4 acc[4] = {};

  int srow = t >> 2;
  int sk   = (t & 3) * 16;
  const size_t abase = (size_t)(bm * TM + srow) * lda + sk;
  const size_t bbase = (size_t)(bn * TN + srow) * ldb + sk;

  uint4 pa0 = *(const uint4*)&A[abase];
  uint4 pa1 = *(const uint4*)&A[abase + 8];
  uint4 pb0 = *(const uint4*)&Bt[bbase];
  uint4 pb1 = *(const uint4*)&Bt[bbase + 8];

  for (int kt = 0; kt < K; kt += 64) {
    *(uint4*)&sA[srow * LDSP + sk]     = pa0;
    *(uint4*)&sA[srow * LDSP + sk + 8] = pa1;
    *(uint4*)&sB[srow * LDSP + sk]     = pb0;
    *(uint4*)&sB[srow * LDSP + sk + 8] = pb1;
    __syncthreads();
    if (kt + 64 < K) {
      pa0 = *(const uint4*)&A[abase + kt + 64];
      pa1 = *(const uint4*)&A[abase + kt + 72];
      pb0 = *(const uint4*)&Bt[bbase + kt + 64];
      pb1 = *(const uint4*)&Bt[bbase + kt + 72];
    }
    bf16x8 af0 = *(const bf16x8*)&sA[(wave * 16 + l16) * LDSP + quad * 8];
    bf16x8 af1 = *(const bf16x8*)&sA[(wave * 16 + l16) * LDSP + 32 + quad * 8];
#pragma unroll
    for (int c = 0; c < 4; ++c) {
      bf16x8 bf0 = *(const bf16x8*)&sB[(c * 16 + l16) * LDSP + quad * 8];
      bf16x8 bf1 = *(const bf16x8*)&sB[(c * 16 + l16) * LDSP + 32 + quad * 8];
      acc[c] = __builtin_amdgcn_mfma_f32_16x16x32_bf16(af0, bf0, acc[c], 0, 0, 0);
      acc[c] = __builtin_amdgcn_mfma_f32_16x16x32_bf16(af1, bf1, acc[c], 0, 0, 0);
    }
    __syncthreads();
  }
  int row0 = bm * TM + wave * 16 + quad * 4;
  int col0 = bn * TN;
#pragma unroll
  for (int c = 0; c < 4; ++c) {
#pragma unroll
    for (int r = 0; r < 4; ++r) {
      C[(size_t)(row0 + r) * ldc + col0 + c * 16 + l16] = __float2bfloat16(acc[c][r]);
    }
  }
}

// ------- h1: 2 rows per block (two independent gather chains) -------
__global__ __launch_bounds__(256) void spmm_h1(const bf16* __restrict__ XW,
                                               const int* __restrict__ ell_cnt,
                                               const u16* __restrict__ ell_col,
                                               const float* __restrict__ b1,
                                               float* __restrict__ out2,
                                               bf16* __restrict__ h1b) {
  __shared__ int sc0[ELLW], sc1[ELLW];
  int r0 = blockIdx.x * 2, r1 = r0 + 1;
  int t = threadIdx.x;
  int nn0 = ell_cnt[r0], nn1 = ell_cnt[r1];
  const u16* c0 = ell_col + (size_t)r0 * ELLW;
  const u16* c1 = ell_col + (size_t)r1 * ELLW;
  for (int k = t; k < nn0; k += 256) sc0[k] = c0[k];
  for (int k = t; k < nn1; k += 256) sc1[k] = c1[k];
  __syncthreads();
  float a0 = 0.f, a1 = 0.f;
#pragma unroll 4
  for (int k = 0; k < nn0; ++k) a0 += __bfloat162float(XW[(size_t)sc0[k] * NHID + t]);
#pragma unroll 4
  for (int k = 0; k < nn1; ++k) a1 += __bfloat162float(XW[(size_t)sc1[k] * NHID + t]);
  float bb = b1[t];
  a0 = fmaxf(a0 + bb, 0.f);
  a1 = fmaxf(a1 + bb, 0.f);
  out2[(size_t)r0 * (NHID + NCLASS) + t] = a0;
  out2[(size_t)r1 * (NHID + NCLASS) + t] = a1;
  h1b[(size_t)r0 * NHID + t] = __float2bfloat16(a0);
  h1b[(size_t)r1 * NHID + t] = __float2bfloat16(a1);
}

// ---------------- f1/f2 ----------------
__global__ __launch_bounds__(256) void f12_kernel(const bf16* __restrict__ Wh,
                                                  const float* __restrict__ avec,
                                                  float* __restrict__ f12) {
  int wave = threadIdx.x >> 6, lane = threadIdx.x & 63;
  int row = blockIdx.x * 4 + wave;
  const bf16* wr = Wh + (size_t)row * NHID;
  float s1 = 0.f, s2 = 0.f;
  for (int k = lane; k < NHID; k += 64) {
    float w = __bfloat162float(wr[k]);
    s1 += w * avec[k];
    s2 += w * avec[NHID + k];
  }
  for (int o = 32; o > 0; o >>= 1) {
    s1 += __shfl_down(s1, o, 64);
    s2 += __shfl_down(s2, o, 64);
  }
  if (lane == 0) { f12[row] = s1; f12[NN + row] = s2; }
}

// ======== PATH A: fused attention — LDS rowbuf single-pass nt-stream ========
__global__ __launch_bounds__(256) void attn_fused(const bf16* __restrict__ Wh,
                                                  const int* __restrict__ ell_cnt,
                                                  const u16* __restrict__ ell_col,
                                                  const float* __restrict__ f12,
                                                  float* __restrict__ att,
                                                  bf16* __restrict__ aout) {
  __shared__ __align__(16) float rowbuf[NN];   // 32 KB
  __shared__ float p[ELLW];
  __shared__ int scols[ELLW];
  __shared__ float red[8];
  int row = blockIdx.x, t = threadIdx.x;
  int nn = ell_cnt[row];
  const u16* cr = ell_col + (size_t)row * ELLW;
  float f1i = f12[row];
  const float* f2 = f12 + NN;

  f32x4* rb4 = (f32x4*)rowbuf;
  f32x4 z = {0.f, 0.f, 0.f, 0.f};
#pragma unroll
  for (int k = t; k < NN / 4; k += 256) rb4[k] = z;
  for (int k = t; k < nn; k += 256) scols[k] = cr[k];
  __syncthreads();

  float lmax = -1e30f;
  for (int k = t; k < nn; k += 256) {
    float e = f1i + f2[scols[k]];
    e = (e > 0.f) ? e : 0.01f * e;
    p[k] = e;
    lmax = fmaxf(lmax, e);
  }
  for (int o = 32; o > 0; o >>= 1) lmax = fmaxf(lmax, __shfl_down(lmax, o, 64));
  if ((t & 63) == 0) red[t >> 6] = lmax;
  __syncthreads();
  float gmax = fmaxf(fmaxf(red[0], red[1]), fmaxf(red[2], red[3]));

  float lsum = 0.f;
  for (int k = t; k < nn; k += 256) {
    float ex = __expf(p[k] - gmax);
    p[k] = ex;
    lsum += ex;
  }
  for (int o = 32; o > 0; o >>= 1) lsum += __shfl_down(lsum, o, 64);
  __syncthreads();
  if ((t & 63) == 0) red[4 + (t >> 6)] = lsum;
  __syncthreads();
  float inv = 1.f / fmaxf(red[4] + red[5] + red[6] + red[7], 1e-30f);

  // scatter into LDS, then ONE clean nt-streamed pass to global (no RMW)
  for (int k = t; k < nn; k += 256) rowbuf[scols[k]] = p[k] * inv;
  __syncthreads();
  f32x4* dst = (f32x4*)(att + (size_t)row * NN);
#pragma unroll
  for (int k = t; k < NN / 4; k += 256) __builtin_nontemporal_store(rb4[k], &dst[k]);

  float acc = 0.f;
#pragma unroll 8
  for (int k = 0; k < nn; ++k)
    acc += p[k] * __bfloat162float(Wh[(size_t)scols[k] * NHID + t]);
  acc *= inv;
  float e = (acc > 0.f) ? acc : (__expf(acc) - 1.f);
  aout[(size_t)row * NHID + t] = __float2bfloat16(e);
}

// ======== PATH A: gc3 fused via associativity: out = ((adj@aout)@W3)+b3 ========
__global__ __launch_bounds__(256) void spmm_gc3(const bf16* __restrict__ aout,
                                                const int* __restrict__ ell_cnt,
                                                const u16* __restrict__ ell_col,
                                                const float* __restrict__ W3,
                                                const float* __restrict__ b3,
                                                float* __restrict__ out2,
                                                float* __restrict__ out0) {
  __shared__ float sW[NHID * NCLASS];   // 16 KB
  __shared__ float s[NHID];
  __shared__ int scols[ELLW];
  int row = blockIdx.x, t = threadIdx.x;
  int nn = ell_cnt[row];
  const u16* cr = ell_col + (size_t)row * ELLW;
  for (int k = t; k < NHID * NCLASS; k += 256) sW[k] = W3[k];
  for (int k = t; k < nn; k += 256) scols[k] = cr[k];
  __syncthreads();
  // s = sum of neighbor aout rows
  float acc = 0.f;
#pragma unroll 8
  for (int k = 0; k < nn; ++k)
    acc += __bfloat162float(aout[(size_t)scols[k] * NHID + t]);
  s[t] = acc;
  __syncthreads();
  // out[row, c] = s . W3[:, c] + b3[c]; 16 threads per c (same wave), shuffle reduce
  int c = t >> 4, j = t & 15;
  float part = 0.f;
#pragma unroll
  for (int k = j; k < NHID; k += 16)
    part += s[k] * sW[k * NCLASS + c];
  part += __shfl_down(part, 8, 64);
  part += __shfl_down(part, 4, 64);
  part += __shfl_down(part, 2, 64);
  part += __shfl_down(part, 1, 64);
  if (j == 0) {
    float v = part + b3[c];
    out2[(size_t)row * (NHID + NCLASS) + NHID + c] = v;
    out0[(size_t)row * NCLASS + c] = 1.f / (1.f + __expf(-v));
  }
}

// ======== PATH B fallback kernels ========
__global__ __launch_bounds__(256) void attn_sparse(const bf16* __restrict__ Wh,
                                                   const int* __restrict__ ell_cnt,
                                                   const u16* __restrict__ ell_col,
                                                   const float* __restrict__ f12,
                                                   bf16* __restrict__ aout) {
  __shared__ float p[ELLW];
  __shared__ int scols[ELLW];
  __shared__ float red[8];
  int row = blockIdx.x, t = threadIdx.x;
  int nn = ell_cnt[row];
  const u16* cr = ell_col + (size_t)row * ELLW;
  float f1i = f12[row];
  const float* f2 = f12 + NN;
  for (int k = t; k < nn; k += 256) scols[k] = cr[k];
  __syncthreads();
  float lmax = -1e30f;
  for (int k = t; k < nn; k += 256) {
    float e = f1i + f2[scols[k]];
    e = (e > 0.f) ? e : 0.01f * e;
    p[k] = e;
    lmax = fmaxf(lmax, e);
  }
  for (int o = 32; o > 0; o >>= 1) lmax = fmaxf(lmax, __shfl_down(lmax, o, 64));
  if ((t & 63) == 0) red[t >> 6] = lmax;
  __syncthreads();
  float gmax = fmaxf(fmaxf(red[0], red[1]), fmaxf(red[2], red[3]));
  float lsum = 0.f;
  for (int k = t; k < nn; k += 256) {
    float ex = __expf(p[k] - gmax);
    p[k] = ex;
    lsum += ex;
  }
  for (int o = 32; o > 0; o >>= 1) lsum += __shfl_down(lsum, o, 64);
  __syncthreads();
  if ((t & 63) == 0) red[4 + (t >> 6)] = lsum;
  __syncthreads();
  float inv = 1.f / fmaxf(red[4] + red[5] + red[6] + red[7], 1e-30f);
  float acc = 0.f;
  for (int k = 0; k < nn; ++k)
    acc += p[k] * __bfloat162float(Wh[(size_t)scols[k] * NHID + t]);
  acc *= inv;
  float e = (acc > 0.f) ? acc : (__expf(acc) - 1.f);
  aout[(size_t)row * NHID + t] = __float2bfloat16(e);
}

__global__ __launch_bounds__(256) void attn_dense(const int* __restrict__ adj,
                                                  const float* __restrict__ f12,
                                                  float* __restrict__ att) {
  __shared__ __align__(16) float rowbuf[NN];
  __shared__ float se[ELLW];
  __shared__ int sj[ELLW];
  __shared__ float red[8];
  __shared__ int cnt;
  int row = blockIdx.x, t = threadIdx.x;
  if (t == 0) cnt = 0;
  f32x4* rb4 = (f32x4*)rowbuf;
  f32x4 z = {0.f, 0.f, 0.f, 0.f};
  for (int k = t; k < NN / 4; k += 256) rb4[k] = z;
  float f1i = f12[row];
  const float* f2 = f12 + NN;
  __syncthreads();
  const int4* arow = (const int4*)(adj + (size_t)row * NN);
  for (int j4 = t; j4 < NN / 4; j4 += 256) {
    int4 v = arow[j4];
    int base = j4 * 4;
    if (v.x) { int p = atomicAdd(&cnt, 1); if (p < ELLW) { sj[p] = base;     se[p] = f1i + f2[base];     } }
    if (v.y) { int p = atomicAdd(&cnt, 1); if (p < ELLW) { sj[p] = base + 1; se[p] = f1i + f2[base + 1]; } }
    if (v.z) { int p = atomicAdd(&cnt, 1); if (p < ELLW) { sj[p] = base + 2; se[p] = f1i + f2[base + 2]; } }
    if (v.w) { int p = atomicAdd(&cnt, 1); if (p < ELLW) { sj[p] = base + 3; se[p] = f1i + f2[base + 3]; } }
  }
  __syncthreads();
  int nn = cnt < ELLW ? cnt : ELLW;
  float lmax = -1e30f;
  for (int k = t; k < nn; k += 256) {
    float e = se[k];
    e = (e > 0.f) ? e : 0.01f * e;
    se[k] = e;
    lmax = fmaxf(lmax, e);
  }
  for (int o = 32; o > 0; o >>= 1) lmax = fmaxf(lmax, __shfl_down(lmax, o, 64));
  if ((t & 63) == 0) red[t >> 6] = lmax;
  __syncthreads();
  float gmax = fmaxf(fmaxf(red[0], red[1]), fmaxf(red[2], red[3]));
  float lsum = 0.f;
  for (int k = t; k < nn; k += 256) {
    float ex = __expf(se[k] - gmax);
    se[k] = ex;
    lsum += ex;
  }
  for (int o = 32; o > 0; o >>= 1) lsum += __shfl_down(lsum, o, 64);
  __syncthreads();
  if ((t & 63) == 0) red[4 + (t >> 6)] = lsum;
  __syncthreads();
  float inv = 1.f / fmaxf(red[4] + red[5] + red[6] + red[7], 1e-30f);
  for (int k = t; k < nn; k += 256) rowbuf[sj[k]] = se[k] * inv;
  __syncthreads();
  const f32x4* src = (const f32x4*)rowbuf;
  f32x4* dst = (f32x4*)(att + (size_t)row * NN);
  for (int k = t; k < NN / 4; k += 256) dst[k] = src[k];
}

// ---------------- A3 = a_out @ W3 (f32) [PATH B] ----------------
__global__ __launch_bounds__(256) void gemm3(const bf16* __restrict__ aout,
                                             const float* __restrict__ W3,
                                             float* __restrict__ A3) {
  __shared__ float sW[NHID * NCLASS];
  __shared__ bf16 sa[16 * NHID];
  int t = threadIdx.x;
  for (int k = t; k < NHID * NCLASS; k += 256) sW[k] = W3[k];
  int r0 = blockIdx.x * 16;
  for (int k = t; k < 16 * NHID; k += 256) sa[k] = aout[(size_t)r0 * NHID + k];
  __syncthreads();
  int r = t >> 4, c = t & 15;
  float acc = 0.f;
#pragma unroll 8
  for (int k = 0; k < NHID; ++k)
    acc += __bfloat162float(sa[r * NHID + k]) * sW[k * NCLASS + c];
  A3[(size_t)(r0 + r) * NCLASS + c] = acc;
}

__global__ __launch_bounds__(256) void spmm_out2(const float* __restrict__ A3,
                                                 const int* __restrict__ ell_cnt,
                                                 const u16* __restrict__ ell_col,
                                                 const float* __restrict__ b3,
                                                 float* __restrict__ out2,
                                                 float* __restrict__ out0,
                                                 int write_sig) {
  int g = blockIdx.x * 256 + threadIdx.x;
  int row = g >> 4, c = g & 15;
  int nn = ell_cnt[row];
  const u16* cr = ell_col + (size_t)row * ELLW;
  float acc = b3[c];
#pragma unroll 8
  for (int k = 0; k < nn; ++k)
    acc += A3[(size_t)cr[k] * NCLASS + c];
  out2[(size_t)row * (NHID + NCLASS) + NHID + c] = acc;
  if (write_sig) out0[g] = 1.f / (1.f + __expf(-acc));
}

__global__ __launch_bounds__(256) void copy_f32(const float* __restrict__ src,
                                                float* __restrict__ dst, int n) {
  int i = blockIdx.x * 256 + threadIdx.x;
  if (i < n) dst[i] = src[i];
}

__global__ __launch_bounds__(256) void sigmoid_from_out2(const float* __restrict__ out2,
                                                         float* __restrict__ out0) {
  int g = blockIdx.x * 256 + threadIdx.x;
  int row = g >> 4, c = g & 15;
  float v = out2[(size_t)row * (NHID + NCLASS) + NHID + c];
  out0[g] = 1.f / (1.f + __expf(-v));
}

extern "C" void kernel_launch(void* const* d_in, const int* in_sizes, int n_in,
                              void* d_out, int out_size, void* d_ws, size_t ws_size,
                              hipStream_t stream) {
  const void* x_raw    = d_in[0];
  const int*  adj      = (const int*)d_in[1];
  const void* W1_raw   = d_in[2];
  const void* b1_raw   = d_in[3];
  const void* Wa_raw   = d_in[4];
  const void* avec_raw = d_in[5];
  const void* W3_raw   = d_in[6];
  const void* b3_raw   = d_in[7];

  float* out0 = (float*)d_out;                               // [8192,16]
  float* out1 = out0 + (size_t)NN * NCLASS;                  // [8192,8192]
  float* out2 = out1 + (size_t)NN * NN;                      // [8192,272]

  const size_t NEED = 36u << 20;
  bool useWS = (d_ws != nullptr) && (ws_size >= NEED);

  char* a = useWS ? (char*)d_ws : (char*)out1;
  size_t o = 0;
  auto carve = [&](size_t bytes) { char* p = a + o; o += (bytes + 4095) & ~(size_t)4095; return p; };
  int*   flag    = (int*)  carve(4096);
  int*   ell_cnt = (int*)  carve((size_t)NN * 4);
  u16*   ell_col = (u16*)  carve((size_t)NN * ELLW * 2);
  bf16*  xc      = (bf16*) carve((size_t)NN * NFEAT * 2);
  bf16*  W1t     = (bf16*) carve((size_t)NHID * NFEAT * 2);
  bf16*  Wat     = (bf16*) carve((size_t)NHID * NHID * 2);
  float* avecf   = (float*)carve((size_t)2 * NHID * 4);
  float* b1f     = (float*)carve((size_t)NHID * 4);
  float* b3f     = (float*)carve((size_t)NCLASS * 4);
  float* W3f     = (float*)carve((size_t)NHID * NCLASS * 4);
  bf16*  XW      = (bf16*) carve((size_t)NN * NHID * 2);
  bf16*  h1b     = (bf16*) carve((size_t)NN * NHID * 2);
  bf16*  Wh      = (bf16*) carve((size_t)NN * NHID * 2);
  float* f12a    = (float*)carve((size_t)2 * NN * 4);
  bf16*  aout    = (bf16*) carve((size_t)NN * NHID * 2);
  float* A3ws    = (float*)carve((size_t)NN * NCLASS * 4);

  float* A3 = useWS ? A3ws : out0;
  float* f12stash = out0;

  (void)hipMemsetAsync(flag, 0, 4, stream);
  probe_dtype2<<<128, 256, 0, stream>>>((const u16*)x_raw, NN * NFEAT,
                                        (const u16*)W1_raw, NFEAT * NHID, flag);
  convert_bf<<<(NN * NFEAT + 255) / 256, 256, 0, stream>>>(x_raw, xc, NN * NFEAT, flag);
  convert_rest<<<256, 256, 0, stream>>>(W1_raw, Wa_raw, b1_raw, avec_raw, W3_raw, b3_raw,
                                        W1t, Wat, b1f, avecf, W3f, b3f, flag);

  build_ell<<<NN, 256, 0, stream>>>(adj, ell_cnt, ell_col);
  gemm_bt<<<dim3(NN / TM, NHID / TN), 256, 0, stream>>>(xc, NFEAT, W1t, NFEAT, XW, NHID, NFEAT);
  spmm_h1<<<NN / 2, 256, 0, stream>>>(XW, ell_cnt, ell_col, b1f, out2, h1b);
  gemm_bt<<<dim3(NN / TM, NHID / TN), 256, 0, stream>>>(h1b, NHID, Wat, NHID, Wh, NHID, NHID);
  f12_kernel<<<NN / 4, 256, 0, stream>>>(Wh, avecf, f12a);

  if (useWS) {
    attn_fused<<<NN, 256, 0, stream>>>(Wh, ell_cnt, ell_col, f12a, out1, aout);
    spmm_gc3<<<NN, 256, 0, stream>>>(aout, ell_cnt, ell_col, W3f, b3f, out2, out0);
  } else {
    attn_sparse<<<NN, 256, 0, stream>>>(Wh, ell_cnt, ell_col, f12a, aout);
    gemm3<<<NN / 16, 256, 0, stream>>>(aout, W3f, A3);
    spmm_out2<<<NN * NCLASS / 256, 256, 0, stream>>>(A3, ell_cnt, ell_col, b3f, out2, out0, 0);
    copy_f32<<<(2 * NN + 255) / 256, 256, 0, stream>>>(f12a, f12stash, 2 * NN);
    attn_dense<<<NN, 256, 0, stream>>>(adj, f12stash, out1);
    sigmoid_from_out2<<<NN * NCLASS / 256, 256, 0, stream>>>(out2, out0);
  }
}

// Round 12
// 642.385 us; speedup vs baseline: 1.0195x; 1.0195x over previous
//
#include <hip/hip_runtime.h>
#include <hip/hip_bf16.h>

#define NN    8192
#define NFEAT 512
#define NHID  256
#define NCLASS 16
#define ELLW  256

typedef __hip_bfloat16 bf16;
typedef unsigned short u16;
typedef __bf16 bf16x8 __attribute__((ext_vector_type(8)));
typedef float  f32x4  __attribute__((ext_vector_type(4)));
typedef int    i32x4  __attribute__((ext_vector_type(4)));

// ---------------- dtype probe ----------------
__global__ __launch_bounds__(256) void probe_dtype2(const u16* __restrict__ a, int na,
                                                    const u16* __restrict__ b, int nb,
                                                    int* __restrict__ cnt) {
  int c = 0;
  for (int i = blockIdx.x * 256 + threadIdx.x; i < na; i += gridDim.x * 256)
    if (((a[i] >> 7) & 0xFF) == 0xFF) c++;
  for (int i = blockIdx.x * 256 + threadIdx.x; i < nb; i += gridDim.x * 256)
    if (((b[i] >> 7) & 0xFF) == 0xFF) c++;
  if (c) atomicAdd(cnt, c);
}

__global__ __launch_bounds__(256) void convert_bf(const void* __restrict__ src,
                                                  bf16* __restrict__ dst, int n,
                                                  const int* __restrict__ flagcnt) {
  bool isf32 = (*flagcnt > 16);
  int i = blockIdx.x * 256 + threadIdx.x;
  if (i < n) {
    if (isf32) dst[i] = __float2bfloat16(((const float*)src)[i]);
    else       dst[i] = ((const bf16*)src)[i];
  }
}

// ---- one launch: W1^T, Wa^T (bf16) + b1/avec/W3/b3 (f32) ----
__global__ __launch_bounds__(256) void convert_rest(const void* __restrict__ W1r,
                                                    const void* __restrict__ War,
                                                    const void* __restrict__ b1r,
                                                    const void* __restrict__ avr,
                                                    const void* __restrict__ W3r,
                                                    const void* __restrict__ b3r,
                                                    bf16* __restrict__ W1t,
                                                    bf16* __restrict__ Wat,
                                                    float* __restrict__ b1f,
                                                    float* __restrict__ avecf,
                                                    float* __restrict__ W3f,
                                                    float* __restrict__ b3f,
                                                    const int* __restrict__ flagcnt) {
  bool isf32 = (*flagcnt > 16);
  auto rd = [&](const void* p, int i) -> float {
    return isf32 ? ((const float*)p)[i] : __bfloat162float(((const bf16*)p)[i]);
  };
  const int n1 = NFEAT * NHID;
  const int n2 = n1 + NHID * NHID;
  const int n3 = n2 + NHID;
  const int n4 = n3 + 2 * NHID;
  const int n5 = n4 + NHID * NCLASS;
  const int n6 = n5 + NCLASS;
  for (int i = blockIdx.x * 256 + threadIdx.x; i < n6; i += gridDim.x * 256) {
    if (i < n1)      { int k = i / NHID, n = i % NHID; W1t[(size_t)n * NFEAT + k] = __float2bfloat16(rd(W1r, i)); }
    else if (i < n2) { int j = i - n1; int k = j / NHID, n = j % NHID; Wat[(size_t)n * NHID + k] = __float2bfloat16(rd(War, j)); }
    else if (i < n3) b1f[i - n2] = rd(b1r, i - n2);
    else if (i < n4) avecf[i - n3] = rd(avr, i - n3);
    else if (i < n5) W3f[i - n4] = rd(W3r, i - n4);
    else             b3f[i - n5] = rd(b3r, i - n5);
  }
}

// ------- adj -> ELL: ballot compaction, nontemporal adj reads -------
__global__ __launch_bounds__(256) void build_ell(const int* __restrict__ adj,
                                                 int* __restrict__ ell_cnt,
                                                 u16* __restrict__ ell_col) {
  __shared__ int cnt;
  int row = blockIdx.x;
  if (threadIdx.x == 0) cnt = 0;
  __syncthreads();
  const i32x4* arow = (const i32x4*)(adj + (size_t)row * NN);
  u16* crow = ell_col + (size_t)row * ELLW;
  int lane = threadIdx.x & 63;
  unsigned long long lt = ((unsigned long long)1 << lane) - 1;
  for (int j4 = threadIdx.x; j4 < NN / 4; j4 += 256) {
    i32x4 v = __builtin_nontemporal_load(&arow[j4]);
    unsigned long long m0 = __ballot(v.x != 0);
    unsigned long long m1 = __ballot(v.y != 0);
    unsigned long long m2 = __ballot(v.z != 0);
    unsigned long long m3 = __ballot(v.w != 0);
    int c0 = __popcll(m0), c1 = __popcll(m1), c2 = __popcll(m2), c3 = __popcll(m3);
    int total = c0 + c1 + c2 + c3;
    int base = 0;
    if (lane == 0 && total) base = atomicAdd(&cnt, total);
    base = __shfl(base, 0, 64);
    int col = j4 * 4;
    if (v.x) { int p = base + __popcll(m0 & lt);                 if (p < ELLW) crow[p] = (u16)col;       }
    if (v.y) { int p = base + c0 + __popcll(m1 & lt);            if (p < ELLW) crow[p] = (u16)(col + 1); }
    if (v.z) { int p = base + c0 + c1 + __popcll(m2 & lt);       if (p < ELLW) crow[p] = (u16)(col + 2); }
    if (v.w) { int p = base + c0 + c1 + c2 + __popcll(m3 & lt);  if (p < ELLW) crow[p] = (u16)(col + 3); }
  }
  __syncthreads();
  if (threadIdx.x == 0) ell_cnt[row] = cnt < ELLW ? cnt : ELLW;
}

// ------- bf16 MFMA GEMM, TK=64, register prefetch across barrier -------
#define TM 64
#define TN 64
#define LDSP 72

__global__ __launch_bounds__(256) void gemm_bt(const bf16* __restrict__ A, int lda,
                                               const bf16* __restrict__ Bt, int ldb,
                                               bf16* __restrict__ C, int ldc, int K) {
  __shared__ __align__(16) bf16 sA[TM * LDSP];
  __shared__ __align__(16) bf16 sB[TN * LDSP];
  int bm = blockIdx.x, bn = blockIdx.y;
  int t = threadIdx.x;
  int wave = t >> 6, lane = t & 63;
  int quad = lane >> 4, l16 = lane & 15;
  f32x4 acc[4] = {};

  int srow = t >> 2;
  int sk   = (t & 3) * 16;
  const size_t abase = (size_t)(bm * TM + srow) * lda + sk;
  const size_t bbase = (size_t)(bn * TN + srow) * ldb + sk;

  uint4 pa0 = *(const uint4*)&A[abase];
  uint4 pa1 = *(const uint4*)&A[abase + 8];
  uint4 pb0 = *(const uint4*)&Bt[bbase];
  uint4 pb1 = *(const uint4*)&Bt[bbase + 8];

  for (int kt = 0; kt < K; kt += 64) {
    *(uint4*)&sA[srow * LDSP + sk]     = pa0;
    *(uint4*)&sA[srow * LDSP + sk + 8] = pa1;
    *(uint4*)&sB[srow * LDSP + sk]     = pb0;
    *(uint4*)&sB[srow * LDSP + sk + 8] = pb1;
    __syncthreads();
    if (kt + 64 < K) {
      pa0 = *(const uint4*)&A[abase + kt + 64];
      pa1 = *(const uint4*)&A[abase + kt + 72];
      pb0 = *(const uint4*)&Bt[bbase + kt + 64];
      pb1 = *(const uint4*)&Bt[bbase + kt + 72];
    }
    bf16x8 af0 = *(const bf16x8*)&sA[(wave * 16 + l16) * LDSP + quad * 8];
    bf16x8 af1 = *(const bf16x8*)&sA[(wave * 16 + l16) * LDSP + 32 + quad * 8];
#pragma unroll
    for (int c = 0; c < 4; ++c) {
      bf16x8 bf0 = *(const bf16x8*)&sB[(c * 16 + l16) * LDSP + quad * 8];
      bf16x8 bf1 = *(const bf16x8*)&sB[(c * 16 + l16) * LDSP + 32 + quad * 8];
      acc[c] = __builtin_amdgcn_mfma_f32_16x16x32_bf16(af0, bf0, acc[c], 0, 0, 0);
      acc[c] = __builtin_amdgcn_mfma_f32_16x16x32_bf16(af1, bf1, acc[c], 0, 0, 0);
    }
    __syncthreads();
  }
  int row0 = bm * TM + wave * 16 + quad * 4;
  int col0 = bn * TN;
#pragma unroll
  for (int c = 0; c < 4; ++c) {
#pragma unroll
    for (int r = 0; r < 4; ++r) {
      C[(size_t)(row0 + r) * ldc + col0 + c * 16 + l16] = __float2bfloat16(acc[c][r]);
    }
  }
}

// ------- h1: 2 rows per block (two independent gather chains) -------
__global__ __launch_bounds__(256) void spmm_h1(const bf16* __restrict__ XW,
                                               const int* __restrict__ ell_cnt,
                                               const u16* __restrict__ ell_col,
                                               const float* __restrict__ b1,
                                               float* __restrict__ out2,
                                               bf16* __restrict__ h1b) {
  __shared__ int sc0[ELLW], sc1[ELLW];
  int r0 = blockIdx.x * 2, r1 = r0 + 1;
  int t = threadIdx.x;
  int nn0 = ell_cnt[r0], nn1 = ell_cnt[r1];
  const u16* c0 = ell_col + (size_t)r0 * ELLW;
  const u16* c1 = ell_col + (size_t)r1 * ELLW;
  for (int k = t; k < nn0; k += 256) sc0[k] = c0[k];
  for (int k = t; k < nn1; k += 256) sc1[k] = c1[k];
  __syncthreads();
  float a0 = 0.f, a1 = 0.f;
#pragma unroll 4
  for (int k = 0; k < nn0; ++k) a0 += __bfloat162float(XW[(size_t)sc0[k] * NHID + t]);
#pragma unroll 4
  for (int k = 0; k < nn1; ++k) a1 += __bfloat162float(XW[(size_t)sc1[k] * NHID + t]);
  float bb = b1[t];
  a0 = fmaxf(a0 + bb, 0.f);
  a1 = fmaxf(a1 + bb, 0.f);
  out2[(size_t)r0 * (NHID + NCLASS) + t] = a0;
  out2[(size_t)r1 * (NHID + NCLASS) + t] = a1;
  h1b[(size_t)r0 * NHID + t] = __float2bfloat16(a0);
  h1b[(size_t)r1 * NHID + t] = __float2bfloat16(a1);
}

// ---------------- f1/f2 ----------------
__global__ __launch_bounds__(256) void f12_kernel(const bf16* __restrict__ Wh,
                                                  const float* __restrict__ avec,
                                                  float* __restrict__ f12) {
  int wave = threadIdx.x >> 6, lane = threadIdx.x & 63;
  int row = blockIdx.x * 4 + wave;
  const bf16* wr = Wh + (size_t)row * NHID;
  float s1 = 0.f, s2 = 0.f;
  for (int k = lane; k < NHID; k += 64) {
    float w = __bfloat162float(wr[k]);
    s1 += w * avec[k];
    s2 += w * avec[NHID + k];
  }
  for (int o = 32; o > 0; o >>= 1) {
    s1 += __shfl_down(s1, o, 64);
    s2 += __shfl_down(s2, o, 64);
  }
  if (lane == 0) { f12[row] = s1; f12[NN + row] = s2; }
}

// ======== PATH A: fused attention — nt zero-stream + scatter + h_prime ========
__global__ __launch_bounds__(256) void attn_fused(const bf16* __restrict__ Wh,
                                                  const int* __restrict__ ell_cnt,
                                                  const u16* __restrict__ ell_col,
                                                  const float* __restrict__ f12,
                                                  float* __restrict__ att,
                                                  bf16* __restrict__ aout) {
  __shared__ float p[ELLW];
  __shared__ int scols[ELLW];
  __shared__ float red[8];
  int row = blockIdx.x, t = threadIdx.x;
  int nn = ell_cnt[row];
  const u16* cr = ell_col + (size_t)row * ELLW;
  float f1i = f12[row];
  const float* f2 = f12 + NN;

  f32x4* dst = (f32x4*)(att + (size_t)row * NN);
  f32x4 z = {0.f, 0.f, 0.f, 0.f};
#pragma unroll
  for (int k = t; k < NN / 4; k += 256) __builtin_nontemporal_store(z, &dst[k]);

  for (int k = t; k < nn; k += 256) scols[k] = cr[k];
  __syncthreads();

  float lmax = -1e30f;
  for (int k = t; k < nn; k += 256) {
    float e = f1i + f2[scols[k]];
    e = (e > 0.f) ? e : 0.01f * e;
    p[k] = e;
    lmax = fmaxf(lmax, e);
  }
  for (int o = 32; o > 0; o >>= 1) lmax = fmaxf(lmax, __shfl_down(lmax, o, 64));
  if ((t & 63) == 0) red[t >> 6] = lmax;
  __syncthreads();
  float gmax = fmaxf(fmaxf(red[0], red[1]), fmaxf(red[2], red[3]));

  float lsum = 0.f;
  for (int k = t; k < nn; k += 256) {
    float ex = __expf(p[k] - gmax);
    p[k] = ex;
    lsum += ex;
  }
  for (int o = 32; o > 0; o >>= 1) lsum += __shfl_down(lsum, o, 64);
  __syncthreads();
  if ((t & 63) == 0) red[4 + (t >> 6)] = lsum;
  __syncthreads();
  float inv = 1.f / fmaxf(red[4] + red[5] + red[6] + red[7], 1e-30f);

  for (int k = t; k < nn; k += 256)
    att[(size_t)row * NN + scols[k]] = p[k] * inv;

  float acc = 0.f;
#pragma unroll 8
  for (int k = 0; k < nn; ++k)
    acc += p[k] * __bfloat162float(Wh[(size_t)scols[k] * NHID + t]);
  acc *= inv;
  float e = (acc > 0.f) ? acc : (__expf(acc) - 1.f);
  aout[(size_t)row * NHID + t] = __float2bfloat16(e);
}

// ======== PATH B fallback kernels ========
__global__ __launch_bounds__(256) void attn_sparse(const bf16* __restrict__ Wh,
                                                   const int* __restrict__ ell_cnt,
                                                   const u16* __restrict__ ell_col,
                                                   const float* __restrict__ f12,
                                                   bf16* __restrict__ aout) {
  __shared__ float p[ELLW];
  __shared__ int scols[ELLW];
  __shared__ float red[8];
  int row = blockIdx.x, t = threadIdx.x;
  int nn = ell_cnt[row];
  const u16* cr = ell_col + (size_t)row * ELLW;
  float f1i = f12[row];
  const float* f2 = f12 + NN;
  for (int k = t; k < nn; k += 256) scols[k] = cr[k];
  __syncthreads();
  float lmax = -1e30f;
  for (int k = t; k < nn; k += 256) {
    float e = f1i + f2[scols[k]];
    e = (e > 0.f) ? e : 0.01f * e;
    p[k] = e;
    lmax = fmaxf(lmax, e);
  }
  for (int o = 32; o > 0; o >>= 1) lmax = fmaxf(lmax, __shfl_down(lmax, o, 64));
  if ((t & 63) == 0) red[t >> 6] = lmax;
  __syncthreads();
  float gmax = fmaxf(fmaxf(red[0], red[1]), fmaxf(red[2], red[3]));
  float lsum = 0.f;
  for (int k = t; k < nn; k += 256) {
    float ex = __expf(p[k] - gmax);
    p[k] = ex;
    lsum += ex;
  }
  for (int o = 32; o > 0; o >>= 1) lsum += __shfl_down(lsum, o, 64);
  __syncthreads();
  if ((t & 63) == 0) red[4 + (t >> 6)] = lsum;
  __syncthreads();
  float inv = 1.f / fmaxf(red[4] + red[5] + red[6] + red[7], 1e-30f);
  float acc = 0.f;
  for (int k = 0; k < nn; ++k)
    acc += p[k] * __bfloat162float(Wh[(size_t)scols[k] * NHID + t]);
  acc *= inv;
  float e = (acc > 0.f) ? acc : (__expf(acc) - 1.f);
  aout[(size_t)row * NHID + t] = __float2bfloat16(e);
}

__global__ __launch_bounds__(256) void attn_dense(const int* __restrict__ adj,
                                                  const float* __restrict__ f12,
                                                  float* __restrict__ att) {
  __shared__ __align__(16) float rowbuf[NN];
  __shared__ float se[ELLW];
  __shared__ int sj[ELLW];
  __shared__ float red[8];
  __shared__ int cnt;
  int row = blockIdx.x, t = threadIdx.x;
  if (t == 0) cnt = 0;
  f32x4* rb4 = (f32x4*)rowbuf;
  f32x4 z = {0.f, 0.f, 0.f, 0.f};
  for (int k = t; k < NN / 4; k += 256) rb4[k] = z;
  float f1i = f12[row];
  const float* f2 = f12 + NN;
  __syncthreads();
  const int4* arow = (const int4*)(adj + (size_t)row * NN);
  for (int j4 = t; j4 < NN / 4; j4 += 256) {
    int4 v = arow[j4];
    int base = j4 * 4;
    if (v.x) { int p = atomicAdd(&cnt, 1); if (p < ELLW) { sj[p] = base;     se[p] = f1i + f2[base];     } }
    if (v.y) { int p = atomicAdd(&cnt, 1); if (p < ELLW) { sj[p] = base + 1; se[p] = f1i + f2[base + 1]; } }
    if (v.z) { int p = atomicAdd(&cnt, 1); if (p < ELLW) { sj[p] = base + 2; se[p] = f1i + f2[base + 2]; } }
    if (v.w) { int p = atomicAdd(&cnt, 1); if (p < ELLW) { sj[p] = base + 3; se[p] = f1i + f2[base + 3]; } }
  }
  __syncthreads();
  int nn = cnt < ELLW ? cnt : ELLW;
  float lmax = -1e30f;
  for (int k = t; k < nn; k += 256) {
    float e = se[k];
    e = (e > 0.f) ? e : 0.01f * e;
    se[k] = e;
    lmax = fmaxf(lmax, e);
  }
  for (int o = 32; o > 0; o >>= 1) lmax = fmaxf(lmax, __shfl_down(lmax, o, 64));
  if ((t & 63) == 0) red[t >> 6] = lmax;
  __syncthreads();
  float gmax = fmaxf(fmaxf(red[0], red[1]), fmaxf(red[2], red[3]));
  float lsum = 0.f;
  for (int k = t; k < nn; k += 256) {
    float ex = __expf(se[k] - gmax);
    se[k] = ex;
    lsum += ex;
  }
  for (int o = 32; o > 0; o >>= 1) lsum += __shfl_down(lsum, o, 64);
  __syncthreads();
  if ((t & 63) == 0) red[4 + (t >> 6)] = lsum;
  __syncthreads();
  float inv = 1.f / fmaxf(red[4] + red[5] + red[6] + red[7], 1e-30f);
  for (int k = t; k < nn; k += 256) rowbuf[sj[k]] = se[k] * inv;
  __syncthreads();
  const f32x4* src = (const f32x4*)rowbuf;
  f32x4* dst = (f32x4*)(att + (size_t)row * NN);
  for (int k = t; k < NN / 4; k += 256) dst[k] = src[k];
}

// ---------------- A3 = a_out @ W3 (f32) ----------------
__global__ __launch_bounds__(256) void gemm3(const bf16* __restrict__ aout,
                                             const float* __restrict__ W3,
                                             float* __restrict__ A3) {
  __shared__ float sW[NHID * NCLASS];
  __shared__ bf16 sa[16 * NHID];
  int t = threadIdx.x;
  for (int k = t; k < NHID * NCLASS; k += 256) sW[k] = W3[k];
  int r0 = blockIdx.x * 16;
  for (int k = t; k < 16 * NHID; k += 256) sa[k] = aout[(size_t)r0 * NHID + k];
  __syncthreads();
  int r = t >> 4, c = t & 15;
  float acc = 0.f;
#pragma unroll 8
  for (int k = 0; k < NHID; ++k)
    acc += __bfloat162float(sa[r * NHID + k]) * sW[k * NCLASS + c];
  A3[(size_t)(r0 + r) * NCLASS + c] = acc;
}

// ------- out2[:,256:272] = spmm(adj, A3) + b3 ; optional sigmoid to out0 -------
__global__ __launch_bounds__(256) void spmm_out2(const float* __restrict__ A3,
                                                 const int* __restrict__ ell_cnt,
                                                 const u16* __restrict__ ell_col,
                                                 const float* __restrict__ b3,
                                                 float* __restrict__ out2,
                                                 float* __restrict__ out0,
                                                 int write_sig) {
  int g = blockIdx.x * 256 + threadIdx.x;
  int row = g >> 4, c = g & 15;
  int nn = ell_cnt[row];
  const u16* cr = ell_col + (size_t)row * ELLW;
  float acc = b3[c];
#pragma unroll 8
  for (int k = 0; k < nn; ++k)
    acc += A3[(size_t)cr[k] * NCLASS + c];
  out2[(size_t)row * (NHID + NCLASS) + NHID + c] = acc;
  if (write_sig) out0[g] = 1.f / (1.f + __expf(-acc));
}

__global__ __launch_bounds__(256) void copy_f32(const float* __restrict__ src,
                                                float* __restrict__ dst, int n) {
  int i = blockIdx.x * 256 + threadIdx.x;
  if (i < n) dst[i] = src[i];
}

__global__ __launch_bounds__(256) void sigmoid_from_out2(const float* __restrict__ out2,
                                                         float* __restrict__ out0) {
  int g = blockIdx.x * 256 + threadIdx.x;
  int row = g >> 4, c = g & 15;
  float v = out2[(size_t)row * (NHID + NCLASS) + NHID + c];
  out0[g] = 1.f / (1.f + __expf(-v));
}

extern "C" void kernel_launch(void* const* d_in, const int* in_sizes, int n_in,
                              void* d_out, int out_size, void* d_ws, size_t ws_size,
                              hipStream_t stream) {
  const void* x_raw    = d_in[0];
  const int*  adj      = (const int*)d_in[1];
  const void* W1_raw   = d_in[2];
  const void* b1_raw   = d_in[3];
  const void* Wa_raw   = d_in[4];
  const void* avec_raw = d_in[5];
  const void* W3_raw   = d_in[6];
  const void* b3_raw   = d_in[7];

  float* out0 = (float*)d_out;                               // [8192,16]
  float* out1 = out0 + (size_t)NN * NCLASS;                  // [8192,8192]
  float* out2 = out1 + (size_t)NN * NN;                      // [8192,272]

  const size_t NEED = 36u << 20;
  bool useWS = (d_ws != nullptr) && (ws_size >= NEED);

  char* a = useWS ? (char*)d_ws : (char*)out1;
  size_t o = 0;
  auto carve = [&](size_t bytes) { char* p = a + o; o += (bytes + 4095) & ~(size_t)4095; return p; };
  int*   flag    = (int*)  carve(4096);
  int*   ell_cnt = (int*)  carve((size_t)NN * 4);
  u16*   ell_col = (u16*)  carve((size_t)NN * ELLW * 2);
  bf16*  xc      = (bf16*) carve((size_t)NN * NFEAT * 2);
  bf16*  W1t     = (bf16*) carve((size_t)NHID * NFEAT * 2);
  bf16*  Wat     = (bf16*) carve((size_t)NHID * NHID * 2);
  float* avecf   = (float*)carve((size_t)2 * NHID * 4);
  float* b1f     = (float*)carve((size_t)NHID * 4);
  float* b3f     = (float*)carve((size_t)NCLASS * 4);
  float* W3f     = (float*)carve((size_t)NHID * NCLASS * 4);
  bf16*  XW      = (bf16*) carve((size_t)NN * NHID * 2);
  bf16*  h1b     = (bf16*) carve((size_t)NN * NHID * 2);
  bf16*  Wh      = (bf16*) carve((size_t)NN * NHID * 2);
  float* f12a    = (float*)carve((size_t)2 * NN * 4);
  bf16*  aout    = (bf16*) carve((size_t)NN * NHID * 2);
  float* A3ws    = (float*)carve((size_t)NN * NCLASS * 4);

  float* A3 = useWS ? A3ws : out0;
  float* f12stash = out0;

  (void)hipMemsetAsync(flag, 0, 4, stream);
  probe_dtype2<<<128, 256, 0, stream>>>((const u16*)x_raw, NN * NFEAT,
                                        (const u16*)W1_raw, NFEAT * NHID, flag);
  convert_bf<<<(NN * NFEAT + 255) / 256, 256, 0, stream>>>(x_raw, xc, NN * NFEAT, flag);
  convert_rest<<<256, 256, 0, stream>>>(W1_raw, Wa_raw, b1_raw, avec_raw, W3_raw, b3_raw,
                                        W1t, Wat, b1f, avecf, W3f, b3f, flag);

  build_ell<<<NN, 256, 0, stream>>>(adj, ell_cnt, ell_col);
  gemm_bt<<<dim3(NN / TM, NHID / TN), 256, 0, stream>>>(xc, NFEAT, W1t, NFEAT, XW, NHID, NFEAT);
  spmm_h1<<<NN / 2, 256, 0, stream>>>(XW, ell_cnt, ell_col, b1f, out2, h1b);
  gemm_bt<<<dim3(NN / TM, NHID / TN), 256, 0, stream>>>(h1b, NHID, Wat, NHID, Wh, NHID, NHID);
  f12_kernel<<<NN / 4, 256, 0, stream>>>(Wh, avecf, f12a);

  if (useWS) {
    attn_fused<<<NN, 256, 0, stream>>>(Wh, ell_cnt, ell_col, f12a, out1, aout);
    gemm3<<<NN / 16, 256, 0, stream>>>(aout, W3f, A3);
    spmm_out2<<<NN * NCLASS / 256, 256, 0, stream>>>(A3, ell_cnt, ell_col, b3f, out2, out0, 1);
  } else {
    attn_sparse<<<NN, 256, 0, stream>>>(Wh, ell_cnt, ell_col, f12a, aout);
    gemm3<<<NN / 16, 256, 0, stream>>>(aout, W3f, A3);
    spmm_out2<<<NN * NCLASS / 256, 256, 0, stream>>>(A3, ell_cnt, ell_col, b3f, out2, out0, 0);
    copy_f32<<<(2 * NN + 255) / 256, 256, 0, stream>>>(f12a, f12stash, 2 * NN);
    attn_dense<<<NN, 256, 0, stream>>>(adj, f12stash, out1);
    sigmoid_from_out2<<<NN * NCLASS / 256, 256, 0, stream>>>(out2, out0);
  }
}